// Round 15
// baseline (324.602 us; speedup 1.0000x reference)
//
#include <hip/hip_runtime.h>
#include <math.h>

#define DIM 128
#define NEG 0.2f
#define EPS 1e-5f
#define LOG2E 1.4426950408889634f

#if __has_builtin(__builtin_amdgcn_exp2f)
#define EXP2(x) __builtin_amdgcn_exp2f(x)
#else
#define EXP2(x) exp2f(x)
#endif

typedef __attribute__((ext_vector_type(8))) short short8v;  // bf16x8 MFMA frag
typedef __attribute__((ext_vector_type(4))) float f32x4;

static __device__ __forceinline__ float leaky(float a) { return a > 0.f ? a : NEG * a; }
static __device__ __forceinline__ float bf2f(unsigned short u) {
    return __uint_as_float(((unsigned int)u) << 16);
}
static __device__ __forceinline__ unsigned short f2bf(float f) {
    unsigned int u = __float_as_uint(f);
    unsigned int r = (u + 0x7fffu + ((u >> 16) & 1u)) >> 16;  // RNE
    return (unsigned short)r;
}

// ---------------- K1: h = x@W via MFMA bf16. Block=256 (4 waves).
// Wave w owns head w = cols [32w, 32w+32). B-frags (W) live in registers;
// grid=1024 amortizes the 64KB W prologue over ~6 chunks.
// hpk word u of row r = channels {c, c+16}, c = 32*(u>>4) + (u&15).
__global__ __launch_bounds__(256) void k_gemm(const float* __restrict__ x,
                                              const float* __restrict__ W,
                                              const float* __restrict__ att_s,
                                              const float* __restrict__ att_d,
                                              unsigned int* __restrict__ hpk,
                                              float* __restrict__ asrc,
                                              float* __restrict__ adst, int n) {
    __shared__ __align__(16) unsigned short xs[16][136];  // 16 rows bf16, padded
    const int tid = threadIdx.x;
    const int w = tid >> 6;    // wave = head
    const int lane = tid & 63;
    const int lm = lane & 15;  // m (A row) / n (B col) index
    const int lk = lane >> 4;  // k-group
    short8v bfrag[2][4];
#pragma unroll
    for (int ct = 0; ct < 2; ++ct) {
        int c = w * 32 + ct * 16 + lm;
#pragma unroll
        for (int q = 0; q < 4; ++q) {
            short8v f;
#pragma unroll
            for (int j = 0; j < 8; ++j) {
                int k = q * 32 + lk * 8 + j;
                f[j] = (short)f2bf(W[k * DIM + c]);
            }
            bfrag[ct][q] = f;
        }
    }
    const float asv0 = att_s[w * 32 + lm] * LOG2E;
    const float asv1 = att_s[w * 32 + 16 + lm] * LOG2E;
    const float adv0 = att_d[w * 32 + lm] * LOG2E;
    const float adv1 = att_d[w * 32 + 16 + lm] * LOG2E;

    const int nchunk = (n + 15) >> 4;
    for (int chunk = blockIdx.x; chunk < nchunk; chunk += gridDim.x) {
        const int r0 = chunk * 16;
        {   // stage 16 rows of x -> bf16 LDS (coalesced 32B/thread)
            int row = tid >> 4;
            int c8 = (tid & 15) * 8;
            int rg = min(r0 + row, n - 1);
            const float4* xp = (const float4*)(x + (size_t)rg * DIM + c8);
            float4 v0 = xp[0], v1 = xp[1];
            short8v t;
            t[0] = (short)f2bf(v0.x); t[1] = (short)f2bf(v0.y);
            t[2] = (short)f2bf(v0.z); t[3] = (short)f2bf(v0.w);
            t[4] = (short)f2bf(v1.x); t[5] = (short)f2bf(v1.y);
            t[6] = (short)f2bf(v1.z); t[7] = (short)f2bf(v1.w);
            *(short8v*)(&xs[row][c8]) = t;
        }
        __syncthreads();
        f32x4 acc0 = {0.f, 0.f, 0.f, 0.f}, acc1 = {0.f, 0.f, 0.f, 0.f};
#pragma unroll
        for (int q = 0; q < 4; ++q) {
            short8v a = *(const short8v*)(&xs[lm][q * 32 + lk * 8]);
            acc0 = __builtin_amdgcn_mfma_f32_16x16x32_bf16(a, bfrag[0][q], acc0, 0, 0, 0);
            acc1 = __builtin_amdgcn_mfma_f32_16x16x32_bf16(a, bfrag[1][q], acc1, 0, 0, 0);
        }
        __syncthreads();  // xs consumed; safe to restage next chunk
        float ps[4], qs[4];
#pragma unroll
        for (int j = 0; j < 4; ++j) {
            ps[j] = acc0[j] * asv0 + acc1[j] * asv1;
            qs[j] = acc0[j] * adv0 + acc1[j] * adv1;
        }
#pragma unroll
        for (int m = 1; m < 16; m <<= 1) {
#pragma unroll
            for (int j = 0; j < 4; ++j) {
                ps[j] += __shfl_xor(ps[j], m);
                qs[j] += __shfl_xor(qs[j], m);
            }
        }
#pragma unroll
        for (int j = 0; j < 4; ++j) {
            int r = r0 + 4 * lk + j;
            if (r < n) {
                hpk[(size_t)r * 64 + 16 * w + lm] =
                    (unsigned int)f2bf(acc0[j]) | ((unsigned int)f2bf(acc1[j]) << 16);
                if (lm == 0) {
                    asrc[r * 4 + w] = ps[j];
                    adst[r * 4 + w] = qs[j];
                }
            }
        }
    }
}

// ---------------- K2: init deg=1 (self loop) and zero BN stats ----------------
__global__ void k_init(int* __restrict__ deg, float* __restrict__ stats, int n) {
    int t = blockIdx.x * blockDim.x + threadIdx.x;
    if (t < n) deg[t] = 1;
    if (t < 256) stats[t] = 0.f;
}

// ---------------- K3: XCD-affine windowed histogram of dst (R13-verified ~-15us)
__global__ __launch_bounds__(256) void k_hist(const int* __restrict__ dst,
                                              int* __restrict__ deg, int E, int n) {
    const int g = blockIdx.x & 7;
    const int gb = blockIdx.x >> 3;
    const int nblk = gridDim.x >> 3;
    const int wsz = (n + 7) >> 3;
    const int lo = g * wsz;
    const int hi = min(lo + wsz, n);
    const int step = nblk * 256;
    for (int t = gb * 256 + threadIdx.x; t < E; t += step) {
        int d = dst[t];
        if (d >= lo && d < hi) atomicAdd(&deg[d], 1);
    }
}

// ---------------- K4abc: device-wide exclusive scan of deg (1024 elems/block) --
__global__ __launch_bounds__(256) void k_scan_part(const int* __restrict__ deg,
                                                   int* __restrict__ bsum, int n) {
    int idx = blockIdx.x * 1024 + threadIdx.x * 4;
    int4 v = {0, 0, 0, 0};
    if (idx + 3 < n) v = *(const int4*)(deg + idx);
    else {
        if (idx + 0 < n) v.x = deg[idx + 0];
        if (idx + 1 < n) v.y = deg[idx + 1];
        if (idx + 2 < n) v.z = deg[idx + 2];
    }
    int s = v.x + v.y + v.z + v.w;
#pragma unroll
    for (int m = 1; m < 64; m <<= 1) s += __shfl_xor(s, m);
    __shared__ int ws[4];
    if ((threadIdx.x & 63) == 0) ws[threadIdx.x >> 6] = s;
    __syncthreads();
    if (threadIdx.x == 0) bsum[blockIdx.x] = ws[0] + ws[1] + ws[2] + ws[3];
}

__global__ __launch_bounds__(256) void k_scan_tops(int* __restrict__ bsum, int B) {
    __shared__ int lds[256];
    int t = threadIdx.x;
    int v = (t < B) ? bsum[t] : 0;
    lds[t] = v;
    __syncthreads();
    int acc = v;
    for (int ofs = 1; ofs < 256; ofs <<= 1) {
        int u = (t >= ofs) ? lds[t - ofs] : 0;
        __syncthreads();
        acc += u;
        lds[t] = acc;
        __syncthreads();
    }
    if (t < B) bsum[t] = acc - v;  // exclusive block offsets (in place)
}

__global__ __launch_bounds__(256) void k_scan_add(const int* __restrict__ deg,
                                                  const int* __restrict__ bsum,
                                                  int* __restrict__ row_start,
                                                  int* __restrict__ cursor, int n, int total) {
    int t = threadIdx.x;
    int idx = blockIdx.x * 1024 + t * 4;
    int4 v = {0, 0, 0, 0};
    if (idx + 3 < n) v = *(const int4*)(deg + idx);
    else {
        if (idx + 0 < n) v.x = deg[idx + 0];
        if (idx + 1 < n) v.y = deg[idx + 1];
        if (idx + 2 < n) v.z = deg[idx + 2];
    }
    int s = v.x + v.y + v.z + v.w;
    __shared__ int lds[256];
    lds[t] = s;
    __syncthreads();
    int acc = s;
    for (int ofs = 1; ofs < 256; ofs <<= 1) {
        int u = (t >= ofs) ? lds[t - ofs] : 0;
        __syncthreads();
        acc += u;
        lds[t] = acc;
        __syncthreads();
    }
    int excl = bsum[blockIdx.x] + acc - s;
    int4 rs;
    rs.x = excl;
    rs.y = rs.x + v.x;
    rs.z = rs.y + v.y;
    rs.w = rs.z + v.z;
    if (idx + 3 < n) {
        *(int4*)(row_start + idx) = rs;
        *(int4*)(cursor + idx) = rs;
    } else {
        if (idx + 0 < n) { row_start[idx + 0] = rs.x; cursor[idx + 0] = rs.x; }
        if (idx + 1 < n) { row_start[idx + 1] = rs.y; cursor[idx + 1] = rs.y; }
        if (idx + 2 < n) { row_start[idx + 2] = rs.z; cursor[idx + 2] = rs.z; }
    }
    if (blockIdx.x == 0 && t == 0) row_start[n] = total;
}

// ---------------- K5: XCD-affine windowed scatter + softmax-weight precompute.
__global__ __launch_bounds__(256) void k_scatter(const int* __restrict__ src,
                                                 const int* __restrict__ dst,
                                                 const float4* __restrict__ asrc4,
                                                 const float4* __restrict__ adst4,
                                                 int* __restrict__ cursor,
                                                 int* __restrict__ csr,
                                                 uint2* __restrict__ pw,
                                                 int E, int n) {
    const int g = blockIdx.x & 7;
    const int gb = blockIdx.x >> 3;
    const int nblk = gridDim.x >> 3;
    const int wsz = (n + 7) >> 3;
    const int lo = g * wsz;
    const int hi = min(lo + wsz, n);
    const int total = E + n;
    const int step = nblk * 256;
    for (int t = gb * 256 + threadIdx.x; t < total; t += step) {
        int d, sv;
        if (t < E) {
            d = dst[t];
            sv = src[t];
        } else {
            d = t - E;
            sv = d;
        }
        if (d >= lo && d < hi) {
            float4 a = asrc4[sv];   // 1.6MB, L2-resident
            float4 b = adst4[d];    // windowed -> L2-local
            float p0 = EXP2(leaky(a.x + b.x));
            float p1 = EXP2(leaky(a.y + b.y));
            float p2 = EXP2(leaky(a.z + b.z));
            float p3 = EXP2(leaky(a.w + b.w));
            int slot = atomicAdd(&cursor[d], 1);
            csr[slot] = sv;
            uint2 o;
            o.x = (unsigned int)f2bf(p0) | ((unsigned int)f2bf(p1) << 16);
            o.y = (unsigned int)f2bf(p2) | ((unsigned int)f2bf(p3) << 16);
            pw[slot] = o;
        }
    }
}

// ---------------- K6: per-dst-node aggregation, QUARTER-WAVE-PER-EDGE.
// Each 16-lane quarter owns one edge and reads its row slice as ONE uint4
// (lane ll covers hpk words 4ll..4ll+3, all in head ll>>2) -> 4 edges per
// gather instruction, 16 edges in flight from 4 loads/lane (structural MLP,
// immune to the allocator folding scalar batches — R8/R13 lesson).
// Cross-quarter totals via shfl_xor(16|32); epilogue on lanes 0-15.
__global__ __launch_bounds__(256) void k_agg(const unsigned int* __restrict__ hw,
                                             const unsigned short* __restrict__ pwh,
                                             const int* __restrict__ row_start,
                                             const int* __restrict__ csr,
                                             const float* __restrict__ prev,
                                             const float* __restrict__ bias,
                                             float* __restrict__ ypre,
                                             float* __restrict__ stats, int n) {
    const int lane = threadIdx.x & 63;
    const int ql = lane >> 4;       // quarter = edge slot within a 4-edge batch
    const int ll = lane & 15;       // 16B slice index within the 256B row
    const int hq = ll >> 2;         // head of my 4 hpk words
    const int wv = threadIdx.x >> 6;
    int wave = blockIdx.x * 4 + wv;
    int nw = gridDim.x * 4;
    float bs_lo[4] = {0.f, 0.f, 0.f, 0.f}, bq_lo[4] = {0.f, 0.f, 0.f, 0.f};
    float bs_hi[4] = {0.f, 0.f, 0.f, 0.f}, bq_hi[4] = {0.f, 0.f, 0.f, 0.f};
    for (int i = wave; i < n; i += nw) {
        int e0 = row_start[i], e1 = row_start[i + 1];
        float s = 0.f;
        float ac_lo[4] = {0.f, 0.f, 0.f, 0.f}, ac_hi[4] = {0.f, 0.f, 0.f, 0.f};
        for (int e = e0; e < e1; e += 16) {  // 4 sub-batches x 4 edges
            int j[4];
            float pp[4];
            uint4 hv[4];
#pragma unroll
            for (int b = 0; b < 4; ++b) {
                int ee = e + b * 4 + ql;
                int ec = min(ee, e1 - 1);
                j[b] = csr[ec];
                pp[b] = (ee < e1) ? bf2f(pwh[ec * 4 + hq]) : 0.f;
            }
#pragma unroll
            for (int b = 0; b < 4; ++b)
                hv[b] = ((const uint4*)(hw + (size_t)j[b] * 64))[ll];
#pragma unroll
            for (int b = 0; b < 4; ++b) {
                s += pp[b];
                unsigned int h0 = hv[b].x, h1 = hv[b].y, h2 = hv[b].z, h3 = hv[b].w;
                ac_lo[0] = fmaf(pp[b], __uint_as_float(h0 << 16), ac_lo[0]);
                ac_hi[0] = fmaf(pp[b], __uint_as_float(h0 & 0xffff0000u), ac_hi[0]);
                ac_lo[1] = fmaf(pp[b], __uint_as_float(h1 << 16), ac_lo[1]);
                ac_hi[1] = fmaf(pp[b], __uint_as_float(h1 & 0xffff0000u), ac_hi[1]);
                ac_lo[2] = fmaf(pp[b], __uint_as_float(h2 << 16), ac_lo[2]);
                ac_hi[2] = fmaf(pp[b], __uint_as_float(h2 & 0xffff0000u), ac_hi[2]);
                ac_lo[3] = fmaf(pp[b], __uint_as_float(h3 << 16), ac_lo[3]);
                ac_hi[3] = fmaf(pp[b], __uint_as_float(h3 & 0xffff0000u), ac_hi[3]);
            }
        }
        // cross-quarter reduce: after xor 16 and 32, every lane holds totals
#pragma unroll
        for (int m = 16; m < 64; m <<= 1) {
            s += __shfl_xor(s, m);
#pragma unroll
            for (int u = 0; u < 4; ++u) {
                ac_lo[u] += __shfl_xor(ac_lo[u], m);
                ac_hi[u] += __shfl_xor(ac_hi[u], m);
            }
        }
        if (ql == 0) {
            float rs = 1.0f / s;
            size_t base = (size_t)i * DIM;
#pragma unroll
            for (int u = 0; u < 4; ++u) {
                int ug = ll * 4 + u;
                int c = 32 * (ug >> 4) + (ug & 15);
                float o_lo = fmaf(ac_lo[u], rs, bias[c] + prev[base + c]);
                float o_hi = fmaf(ac_hi[u], rs, bias[c + 16] + prev[base + c + 16]);
                ypre[base + c] = o_lo;
                ypre[base + c + 16] = o_hi;
                bs_lo[u] += o_lo; bq_lo[u] = fmaf(o_lo, o_lo, bq_lo[u]);
                bs_hi[u] += o_hi; bq_hi[u] = fmaf(o_hi, o_hi, bq_hi[u]);
            }
        }
    }
    // BN stats: lanes<16 of each wave cover all 128 channels; LDS reduce.
    __shared__ float rsum[128][4];
    __shared__ float rsq[128][4];
    if (ql == 0) {
#pragma unroll
        for (int u = 0; u < 4; ++u) {
            int ug = ll * 4 + u;
            int c = 32 * (ug >> 4) + (ug & 15);
            rsum[c][wv] = bs_lo[u];
            rsum[c + 16][wv] = bs_hi[u];
            rsq[c][wv] = bq_lo[u];
            rsq[c + 16][wv] = bq_hi[u];
        }
    }
    __syncthreads();
    if (threadIdx.x < 128) {
        int c = threadIdx.x;
        atomicAdd(&stats[c], rsum[c][0] + rsum[c][1] + rsum[c][2] + rsum[c][3]);
        atomicAdd(&stats[128 + c], rsq[c][0] + rsq[c][1] + rsq[c][2] + rsq[c][3]);
    }
}

// ---------------- K7: finalize BN scale/shift ----------------
__global__ void k_bnfin(const float* __restrict__ stats, const float* __restrict__ gamma,
                        const float* __restrict__ beta, float* __restrict__ AB, int n) {
    int c = threadIdx.x;  // 128 threads
    float fn = (float)n;
    float mean = stats[c] / fn;
    float var = stats[128 + c] / fn - mean * mean;
    float a = gamma[c] * rsqrtf(var + EPS);
    AB[c] = a;
    AB[128 + c] = beta[c] - mean * a;
}

// ---------------- K8: y = relu(y*A + B), in place, float4 ----------------
__global__ __launch_bounds__(256) void k_final(float* __restrict__ y,
                                               const float* __restrict__ AB, int total4) {
    int t0 = blockIdx.x * blockDim.x + threadIdx.x;
    int stride = gridDim.x * blockDim.x;
    for (int t = t0; t < total4; t += stride) {
        float4 v = ((float4*)y)[t];
        int c0 = (t * 4) & 127;
        v.x = fmaf(v.x, AB[c0 + 0], AB[128 + c0 + 0]);
        v.y = fmaf(v.y, AB[c0 + 1], AB[128 + c0 + 1]);
        v.z = fmaf(v.z, AB[c0 + 2], AB[128 + c0 + 2]);
        v.w = fmaf(v.w, AB[c0 + 3], AB[128 + c0 + 3]);
        v.x = v.x > 0.f ? v.x : 0.f;
        v.y = v.y > 0.f ? v.y : 0.f;
        v.z = v.z > 0.f ? v.z : 0.f;
        v.w = v.w > 0.f ? v.w : 0.f;
        ((float4*)y)[t] = v;
    }
}

extern "C" void kernel_launch(void* const* d_in, const int* in_sizes, int n_in,
                              void* d_out, int out_size, void* d_ws, size_t ws_size,
                              hipStream_t stream) {
    const float* prev  = (const float*)d_in[0];
    const float* x     = (const float*)d_in[1];
    const int*   ei    = (const int*)d_in[2];
    const float* W     = (const float*)d_in[3];
    const float* att_s = (const float*)d_in[4];
    const float* att_d = (const float*)d_in[5];
    const float* bias  = (const float*)d_in[6];
    const float* gamma = (const float*)d_in[7];
    const float* beta  = (const float*)d_in[8];
    const int n = in_sizes[0] / DIM;
    const int E = in_sizes[2] / 2;
    const int* src = ei;
    const int* dst = ei + E;

    char* p = (char*)d_ws;
    auto alloc = [&](size_t bytes) {
        void* q = (void*)p;
        p += (bytes + 255) & ~(size_t)255;
        return q;
    };
    unsigned int* hpk = (unsigned int*)alloc((size_t)n * 64 * 4);
    float* asrc      = (float*)alloc((size_t)n * 4 * 4);
    float* adst      = (float*)alloc((size_t)n * 4 * 4);
    int*   deg       = (int*)alloc((size_t)(n + 1) * 4);
    int*   row_start = (int*)alloc((size_t)(n + 1) * 4);
    int*   cursor    = (int*)alloc((size_t)(n + 1) * 4);
    int*   csr       = (int*)alloc((size_t)(E + n + 16) * 4);
    uint2* pw        = (uint2*)alloc((size_t)(E + n + 16) * 8);  // bf16x4 / edge
    int*   bsum      = (int*)alloc(1024 * 4);
    float* stats     = (float*)alloc(256 * 4);
    float* AB        = (float*)alloc(256 * 4);
    float* yout      = (float*)d_out;

    int B = (n + 1023) / 1024;  // scan blocks (<=256 for n<=262144)
    k_init<<<dim3((n + 255) / 256), dim3(256), 0, stream>>>(deg, stats, n);
    k_gemm<<<dim3(1024), dim3(256), 0, stream>>>(x, W, att_s, att_d, hpk, asrc, adst, n);
    k_hist<<<dim3(2048), dim3(256), 0, stream>>>(dst, deg, E, n);
    k_scan_part<<<dim3(B), dim3(256), 0, stream>>>(deg, bsum, n);
    k_scan_tops<<<dim3(1), dim3(256), 0, stream>>>(bsum, B);
    k_scan_add<<<dim3(B), dim3(256), 0, stream>>>(deg, bsum, row_start, cursor, n, E + n);
    k_scatter<<<dim3(2048), dim3(256), 0, stream>>>(src, dst, (const float4*)asrc,
                                                    (const float4*)adst, cursor, csr, pw, E, n);
    k_agg<<<dim3(2048), dim3(256), 0, stream>>>(hpk, (const unsigned short*)pw, row_start,
                                                csr, prev, bias, yout, stats, n);
    k_bnfin<<<dim3(1), dim3(128), 0, stream>>>(stats, gamma, beta, AB, n);
    int total4 = n * DIM / 4;
    k_final<<<dim3(2048), dim3(256), 0, stream>>>(yout, AB, total4);
}

// Round 16
// 312.186 us; speedup vs baseline: 1.0398x; 1.0398x over previous
//
#include <hip/hip_runtime.h>
#include <math.h>

#define DIM 128
#define NEG 0.2f
#define EPS 1e-5f
#define LOG2E 1.4426950408889634f

#if __has_builtin(__builtin_amdgcn_exp2f)
#define EXP2(x) __builtin_amdgcn_exp2f(x)
#else
#define EXP2(x) exp2f(x)
#endif

typedef __attribute__((ext_vector_type(8))) short short8v;  // bf16x8 MFMA frag
typedef __attribute__((ext_vector_type(4))) float f32x4;

static __device__ __forceinline__ float leaky(float a) { return a > 0.f ? a : NEG * a; }
static __device__ __forceinline__ float bf2f(unsigned short u) {
    return __uint_as_float(((unsigned int)u) << 16);
}
static __device__ __forceinline__ unsigned short f2bf(float f) {
    unsigned int u = __float_as_uint(f);
    unsigned int r = (u + 0x7fffu + ((u >> 16) & 1u)) >> 16;  // RNE
    return (unsigned short)r;
}

// ---------------- K1: h = x@W via MFMA bf16. Block=256 (4 waves).
// Wave w owns head w = cols [32w, 32w+32). B-frags (W) live in registers;
// grid=1024 amortizes the 64KB W prologue over ~6 chunks (R13: -15us w/ hist).
// hpk word u of row r = channels {c, c+16}, c = 32*(u>>4) + (u&15).
__global__ __launch_bounds__(256) void k_gemm(const float* __restrict__ x,
                                              const float* __restrict__ W,
                                              const float* __restrict__ att_s,
                                              const float* __restrict__ att_d,
                                              unsigned int* __restrict__ hpk,
                                              float* __restrict__ asrc,
                                              float* __restrict__ adst, int n) {
    __shared__ __align__(16) unsigned short xs[16][136];  // 16 rows bf16, padded
    const int tid = threadIdx.x;
    const int w = tid >> 6;    // wave = head
    const int lane = tid & 63;
    const int lm = lane & 15;  // m (A row) / n (B col) index
    const int lk = lane >> 4;  // k-group
    short8v bfrag[2][4];
#pragma unroll
    for (int ct = 0; ct < 2; ++ct) {
        int c = w * 32 + ct * 16 + lm;
#pragma unroll
        for (int q = 0; q < 4; ++q) {
            short8v f;
#pragma unroll
            for (int j = 0; j < 8; ++j) {
                int k = q * 32 + lk * 8 + j;
                f[j] = (short)f2bf(W[k * DIM + c]);
            }
            bfrag[ct][q] = f;
        }
    }
    const float asv0 = att_s[w * 32 + lm] * LOG2E;
    const float asv1 = att_s[w * 32 + 16 + lm] * LOG2E;
    const float adv0 = att_d[w * 32 + lm] * LOG2E;
    const float adv1 = att_d[w * 32 + 16 + lm] * LOG2E;

    const int nchunk = (n + 15) >> 4;
    for (int chunk = blockIdx.x; chunk < nchunk; chunk += gridDim.x) {
        const int r0 = chunk * 16;
        {   // stage 16 rows of x -> bf16 LDS (coalesced 32B/thread)
            int row = tid >> 4;
            int c8 = (tid & 15) * 8;
            int rg = min(r0 + row, n - 1);
            const float4* xp = (const float4*)(x + (size_t)rg * DIM + c8);
            float4 v0 = xp[0], v1 = xp[1];
            short8v t;
            t[0] = (short)f2bf(v0.x); t[1] = (short)f2bf(v0.y);
            t[2] = (short)f2bf(v0.z); t[3] = (short)f2bf(v0.w);
            t[4] = (short)f2bf(v1.x); t[5] = (short)f2bf(v1.y);
            t[6] = (short)f2bf(v1.z); t[7] = (short)f2bf(v1.w);
            *(short8v*)(&xs[row][c8]) = t;
        }
        __syncthreads();
        f32x4 acc0 = {0.f, 0.f, 0.f, 0.f}, acc1 = {0.f, 0.f, 0.f, 0.f};
#pragma unroll
        for (int q = 0; q < 4; ++q) {
            short8v a = *(const short8v*)(&xs[lm][q * 32 + lk * 8]);
            acc0 = __builtin_amdgcn_mfma_f32_16x16x32_bf16(a, bfrag[0][q], acc0, 0, 0, 0);
            acc1 = __builtin_amdgcn_mfma_f32_16x16x32_bf16(a, bfrag[1][q], acc1, 0, 0, 0);
        }
        __syncthreads();  // xs consumed; safe to restage next chunk
        float ps[4], qs[4];
#pragma unroll
        for (int j = 0; j < 4; ++j) {
            ps[j] = acc0[j] * asv0 + acc1[j] * asv1;
            qs[j] = acc0[j] * adv0 + acc1[j] * adv1;
        }
#pragma unroll
        for (int m = 1; m < 16; m <<= 1) {
#pragma unroll
            for (int j = 0; j < 4; ++j) {
                ps[j] += __shfl_xor(ps[j], m);
                qs[j] += __shfl_xor(qs[j], m);
            }
        }
#pragma unroll
        for (int j = 0; j < 4; ++j) {
            int r = r0 + 4 * lk + j;
            if (r < n) {
                hpk[(size_t)r * 64 + 16 * w + lm] =
                    (unsigned int)f2bf(acc0[j]) | ((unsigned int)f2bf(acc1[j]) << 16);
                if (lm == 0) {
                    asrc[r * 4 + w] = ps[j];
                    adst[r * 4 + w] = qs[j];
                }
            }
        }
    }
}

// ---------------- K2: init deg=1 (self loop) and zero BN stats ----------------
__global__ void k_init(int* __restrict__ deg, float* __restrict__ stats, int n) {
    int t = blockIdx.x * blockDim.x + threadIdx.x;
    if (t < n) deg[t] = 1;
    if (t < 256) stats[t] = 0.f;
}

// ---------------- K3: XCD-affine windowed histogram of dst (R13-verified ~-15us)
__global__ __launch_bounds__(256) void k_hist(const int* __restrict__ dst,
                                              int* __restrict__ deg, int E, int n) {
    const int g = blockIdx.x & 7;
    const int gb = blockIdx.x >> 3;
    const int nblk = gridDim.x >> 3;
    const int wsz = (n + 7) >> 3;
    const int lo = g * wsz;
    const int hi = min(lo + wsz, n);
    const int step = nblk * 256;
    for (int t = gb * 256 + threadIdx.x; t < E; t += step) {
        int d = dst[t];
        if (d >= lo && d < hi) atomicAdd(&deg[d], 1);
    }
}

// ---------------- K4abc: device-wide exclusive scan of deg (1024 elems/block) --
__global__ __launch_bounds__(256) void k_scan_part(const int* __restrict__ deg,
                                                   int* __restrict__ bsum, int n) {
    int idx = blockIdx.x * 1024 + threadIdx.x * 4;
    int4 v = {0, 0, 0, 0};
    if (idx + 3 < n) v = *(const int4*)(deg + idx);
    else {
        if (idx + 0 < n) v.x = deg[idx + 0];
        if (idx + 1 < n) v.y = deg[idx + 1];
        if (idx + 2 < n) v.z = deg[idx + 2];
    }
    int s = v.x + v.y + v.z + v.w;
#pragma unroll
    for (int m = 1; m < 64; m <<= 1) s += __shfl_xor(s, m);
    __shared__ int ws[4];
    if ((threadIdx.x & 63) == 0) ws[threadIdx.x >> 6] = s;
    __syncthreads();
    if (threadIdx.x == 0) bsum[blockIdx.x] = ws[0] + ws[1] + ws[2] + ws[3];
}

__global__ __launch_bounds__(256) void k_scan_tops(int* __restrict__ bsum, int B) {
    __shared__ int lds[256];
    int t = threadIdx.x;
    int v = (t < B) ? bsum[t] : 0;
    lds[t] = v;
    __syncthreads();
    int acc = v;
    for (int ofs = 1; ofs < 256; ofs <<= 1) {
        int u = (t >= ofs) ? lds[t - ofs] : 0;
        __syncthreads();
        acc += u;
        lds[t] = acc;
        __syncthreads();
    }
    if (t < B) bsum[t] = acc - v;  // exclusive block offsets (in place)
}

__global__ __launch_bounds__(256) void k_scan_add(const int* __restrict__ deg,
                                                  const int* __restrict__ bsum,
                                                  int* __restrict__ row_start,
                                                  int* __restrict__ cursor, int n, int total) {
    int t = threadIdx.x;
    int idx = blockIdx.x * 1024 + t * 4;
    int4 v = {0, 0, 0, 0};
    if (idx + 3 < n) v = *(const int4*)(deg + idx);
    else {
        if (idx + 0 < n) v.x = deg[idx + 0];
        if (idx + 1 < n) v.y = deg[idx + 1];
        if (idx + 2 < n) v.z = deg[idx + 2];
    }
    int s = v.x + v.y + v.z + v.w;
    __shared__ int lds[256];
    lds[t] = s;
    __syncthreads();
    int acc = s;
    for (int ofs = 1; ofs < 256; ofs <<= 1) {
        int u = (t >= ofs) ? lds[t - ofs] : 0;
        __syncthreads();
        acc += u;
        lds[t] = acc;
        __syncthreads();
    }
    int excl = bsum[blockIdx.x] + acc - s;
    int4 rs;
    rs.x = excl;
    rs.y = rs.x + v.x;
    rs.z = rs.y + v.y;
    rs.w = rs.z + v.z;
    if (idx + 3 < n) {
        *(int4*)(row_start + idx) = rs;
        *(int4*)(cursor + idx) = rs;
    } else {
        if (idx + 0 < n) { row_start[idx + 0] = rs.x; cursor[idx + 0] = rs.x; }
        if (idx + 1 < n) { row_start[idx + 1] = rs.y; cursor[idx + 1] = rs.y; }
        if (idx + 2 < n) { row_start[idx + 2] = rs.z; cursor[idx + 2] = rs.z; }
    }
    if (blockIdx.x == 0 && t == 0) row_start[n] = total;
}

// ---------------- K5: XCD-affine windowed scatter + softmax-weight precompute.
// src[t] is read ONLY for edges inside this group's window (7/8 of edges skip
// it) -> read traffic 102MB -> ~58MB. csr/pw/cursor lines written by ONE XCD
// (R11-verified dense L2 merge).
__global__ __launch_bounds__(256) void k_scatter(const int* __restrict__ src,
                                                 const int* __restrict__ dst,
                                                 const float4* __restrict__ asrc4,
                                                 const float4* __restrict__ adst4,
                                                 int* __restrict__ cursor,
                                                 int* __restrict__ csr,
                                                 uint2* __restrict__ pw,
                                                 int E, int n) {
    const int g = blockIdx.x & 7;
    const int gb = blockIdx.x >> 3;
    const int nblk = gridDim.x >> 3;
    const int wsz = (n + 7) >> 3;
    const int lo = g * wsz;
    const int hi = min(lo + wsz, n);
    const int total = E + n;
    const int step = nblk * 256;
    for (int t = gb * 256 + threadIdx.x; t < total; t += step) {
        int d = (t < E) ? dst[t] : (t - E);
        if (d >= lo && d < hi) {
            int sv = (t < E) ? src[t] : d;   // deferred: only window hits read src
            float4 a = asrc4[sv];   // 1.6MB, L2-resident
            float4 b = adst4[d];    // windowed -> L2-local
            float p0 = EXP2(leaky(a.x + b.x));
            float p1 = EXP2(leaky(a.y + b.y));
            float p2 = EXP2(leaky(a.z + b.z));
            float p3 = EXP2(leaky(a.w + b.w));
            int slot = atomicAdd(&cursor[d], 1);
            csr[slot] = sv;
            uint2 o;
            o.x = (unsigned int)f2bf(p0) | ((unsigned int)f2bf(p1) << 16);
            o.y = (unsigned int)f2bf(p2) | ((unsigned int)f2bf(p3) << 16);
            pw[slot] = o;
        }
    }
}

// ---------------- K6: per-dst-node aggregation, weights precomputed.
// R12/R14 body — empirical best (118us) across 4 variants (R13 bounds-split,
// R15 quarter-wave both regressed). Clamp-masked 16-edge batches.
// Lane l: channels {c, c+16}, c = 32*(l>>4)+(l&15); head l>>4.
__global__ __launch_bounds__(256) void k_agg(const unsigned int* __restrict__ hw,
                                             const unsigned short* __restrict__ pwh,
                                             const int* __restrict__ row_start,
                                             const int* __restrict__ csr,
                                             const float* __restrict__ prev,
                                             const float* __restrict__ bias,
                                             float* __restrict__ ypre,
                                             float* __restrict__ stats, int n) {
    const int lane = threadIdx.x & 63;
    const int hd = lane >> 4;                 // head
    const int ch = 32 * hd + (lane & 15);     // channel pair {ch, ch+16}
    int wave = blockIdx.x * 4 + (threadIdx.x >> 6);
    int nw = gridDim.x * 4;
    const float bb0 = bias[ch], bb1 = bias[ch + 16];
    float bsum0 = 0.f, bsq0 = 0.f, bsum1 = 0.f, bsq1 = 0.f;
    for (int i0 = wave; i0 < n; i0 += nw) {
        int i = __builtin_amdgcn_readfirstlane(i0);
        int e0 = row_start[i], e1 = row_start[i + 1];
        float s = 0.f, acc0 = 0.f, acc1 = 0.f;
        for (int e = e0; e < e1; e += 16) {
            int j[16];
            float p[16];
            unsigned int hp[16];
#pragma unroll
            for (int r = 0; r < 16; ++r) {
                int ec = min(e + r, e1 - 1);
                j[r] = csr[ec];
                p[r] = bf2f(pwh[ec * 4 + hd]);
            }
#pragma unroll
            for (int r = 0; r < 16; ++r) hp[r] = hw[(size_t)j[r] * 64 + lane];
#pragma unroll
            for (int r = 0; r < 16; ++r) {
                float pp = (e + r < e1) ? p[r] : 0.f;
                s += pp;
                acc0 = fmaf(pp, __uint_as_float(hp[r] << 16), acc0);
                acc1 = fmaf(pp, __uint_as_float(hp[r] & 0xffff0000u), acc1);
            }
        }
        float rs = 1.0f / s;
        size_t base = (size_t)i * DIM;
        float o0 = fmaf(acc0, rs, bb0 + prev[base + ch]);
        float o1 = fmaf(acc1, rs, bb1 + prev[base + ch + 16]);
        ypre[base + ch] = o0;
        ypre[base + ch + 16] = o1;
        bsum0 += o0; bsq0 = fmaf(o0, o0, bsq0);
        bsum1 += o1; bsq1 = fmaf(o1, o1, bsq1);
    }
    __shared__ float red[4][256];
    red[0][threadIdx.x] = bsum0;
    red[1][threadIdx.x] = bsq0;
    red[2][threadIdx.x] = bsum1;
    red[3][threadIdx.x] = bsq1;
    __syncthreads();
    if (threadIdx.x < 64) {
        int t = threadIdx.x;
        int c = 32 * (t >> 4) + (t & 15);
        float v0 = red[0][t] + red[0][t + 64] + red[0][t + 128] + red[0][t + 192];
        float v1 = red[1][t] + red[1][t + 64] + red[1][t + 128] + red[1][t + 192];
        float v2 = red[2][t] + red[2][t + 64] + red[2][t + 128] + red[2][t + 192];
        float v3 = red[3][t] + red[3][t + 64] + red[3][t + 128] + red[3][t + 192];
        atomicAdd(&stats[c], v0);             // sum, channel c
        atomicAdd(&stats[c + 16], v2);        // sum, channel c+16
        atomicAdd(&stats[128 + c], v1);       // sumsq, channel c
        atomicAdd(&stats[128 + c + 16], v3);  // sumsq, channel c+16
    }
}

// ---------------- K7: finalize BN scale/shift ----------------
__global__ void k_bnfin(const float* __restrict__ stats, const float* __restrict__ gamma,
                        const float* __restrict__ beta, float* __restrict__ AB, int n) {
    int c = threadIdx.x;  // 128 threads
    float fn = (float)n;
    float mean = stats[c] / fn;
    float var = stats[128 + c] / fn - mean * mean;
    float a = gamma[c] * rsqrtf(var + EPS);
    AB[c] = a;
    AB[128 + c] = beta[c] - mean * a;
}

// ---------------- K8: y = relu(y*A + B), in place, float4 ----------------
__global__ __launch_bounds__(256) void k_final(float* __restrict__ y,
                                               const float* __restrict__ AB, int total4) {
    int t0 = blockIdx.x * blockDim.x + threadIdx.x;
    int stride = gridDim.x * blockDim.x;
    for (int t = t0; t < total4; t += stride) {
        float4 v = ((float4*)y)[t];
        int c0 = (t * 4) & 127;
        v.x = fmaf(v.x, AB[c0 + 0], AB[128 + c0 + 0]);
        v.y = fmaf(v.y, AB[c0 + 1], AB[128 + c0 + 1]);
        v.z = fmaf(v.z, AB[c0 + 2], AB[128 + c0 + 2]);
        v.w = fmaf(v.w, AB[c0 + 3], AB[128 + c0 + 3]);
        v.x = v.x > 0.f ? v.x : 0.f;
        v.y = v.y > 0.f ? v.y : 0.f;
        v.z = v.z > 0.f ? v.z : 0.f;
        v.w = v.w > 0.f ? v.w : 0.f;
        ((float4*)y)[t] = v;
    }
}

extern "C" void kernel_launch(void* const* d_in, const int* in_sizes, int n_in,
                              void* d_out, int out_size, void* d_ws, size_t ws_size,
                              hipStream_t stream) {
    const float* prev  = (const float*)d_in[0];
    const float* x     = (const float*)d_in[1];
    const int*   ei    = (const int*)d_in[2];
    const float* W     = (const float*)d_in[3];
    const float* att_s = (const float*)d_in[4];
    const float* att_d = (const float*)d_in[5];
    const float* bias  = (const float*)d_in[6];
    const float* gamma = (const float*)d_in[7];
    const float* beta  = (const float*)d_in[8];
    const int n = in_sizes[0] / DIM;
    const int E = in_sizes[2] / 2;
    const int* src = ei;
    const int* dst = ei + E;

    char* p = (char*)d_ws;
    auto alloc = [&](size_t bytes) {
        void* q = (void*)p;
        p += (bytes + 255) & ~(size_t)255;
        return q;
    };
    unsigned int* hpk = (unsigned int*)alloc((size_t)n * 64 * 4);
    float* asrc      = (float*)alloc((size_t)n * 4 * 4);
    float* adst      = (float*)alloc((size_t)n * 4 * 4);
    int*   deg       = (int*)alloc((size_t)(n + 1) * 4);
    int*   row_start = (int*)alloc((size_t)(n + 1) * 4);
    int*   cursor    = (int*)alloc((size_t)(n + 1) * 4);
    int*   csr       = (int*)alloc((size_t)(E + n + 16) * 4);
    uint2* pw        = (uint2*)alloc((size_t)(E + n + 16) * 8);  // bf16x4 / edge
    int*   bsum      = (int*)alloc(1024 * 4);
    float* stats     = (float*)alloc(256 * 4);
    float* AB        = (float*)alloc(256 * 4);
    float* yout      = (float*)d_out;

    int B = (n + 1023) / 1024;  // scan blocks (<=256 for n<=262144)
    k_init<<<dim3((n + 255) / 256), dim3(256), 0, stream>>>(deg, stats, n);
    k_gemm<<<dim3(1024), dim3(256), 0, stream>>>(x, W, att_s, att_d, hpk, asrc, adst, n);
    k_hist<<<dim3(2048), dim3(256), 0, stream>>>(dst, deg, E, n);
    k_scan_part<<<dim3(B), dim3(256), 0, stream>>>(deg, bsum, n);
    k_scan_tops<<<dim3(1), dim3(256), 0, stream>>>(bsum, B);
    k_scan_add<<<dim3(B), dim3(256), 0, stream>>>(deg, bsum, row_start, cursor, n, E + n);
    k_scatter<<<dim3(2048), dim3(256), 0, stream>>>(src, dst, (const float4*)asrc,
                                                    (const float4*)adst, cursor, csr, pw, E, n);
    k_agg<<<dim3(2048), dim3(256), 0, stream>>>(hpk, (const unsigned short*)pw, row_start,
                                                csr, prev, bias, yout, stats, n);
    k_bnfin<<<dim3(1), dim3(128), 0, stream>>>(stats, gamma, beta, AB, n);
    int total4 = n * DIM / 4;
    k_final<<<dim3(2048), dim3(256), 0, stream>>>(yout, AB, total4);
}

// Round 17
// 298.155 us; speedup vs baseline: 1.0887x; 1.0471x over previous
//
#include <hip/hip_runtime.h>
#include <math.h>

#define DIM 128
#define NEG 0.2f
#define EPS 1e-5f
#define LOG2E 1.4426950408889634f

#if __has_builtin(__builtin_amdgcn_exp2f)
#define EXP2(x) __builtin_amdgcn_exp2f(x)
#else
#define EXP2(x) exp2f(x)
#endif

typedef __attribute__((ext_vector_type(8))) short short8v;  // bf16x8 MFMA frag
typedef __attribute__((ext_vector_type(4))) float f32x4;

static __device__ __forceinline__ float leaky(float a) { return a > 0.f ? a : NEG * a; }
static __device__ __forceinline__ float bf2f(unsigned short u) {
    return __uint_as_float(((unsigned int)u) << 16);
}
static __device__ __forceinline__ unsigned short f2bf(float f) {
    unsigned int u = __float_as_uint(f);
    unsigned int r = (u + 0x7fffu + ((u >> 16) & 1u)) >> 16;  // RNE
    return (unsigned short)r;
}

// ---------------- K1: h = x@W via MFMA bf16. Block=256 (4 waves).
// Wave w owns head w = cols [32w, 32w+32). B-frags (W) live in registers;
// grid=1024 amortizes the 64KB W prologue over ~6 chunks.
// hpk word u of row r = channels {c, c+16}, c = 32*(u>>4) + (u&15).
__global__ __launch_bounds__(256) void k_gemm(const float* __restrict__ x,
                                              const float* __restrict__ W,
                                              const float* __restrict__ att_s,
                                              const float* __restrict__ att_d,
                                              unsigned int* __restrict__ hpk,
                                              float* __restrict__ asrc,
                                              float* __restrict__ adst, int n) {
    __shared__ __align__(16) unsigned short xs[16][136];  // 16 rows bf16, padded
    const int tid = threadIdx.x;
    const int w = tid >> 6;    // wave = head
    const int lane = tid & 63;
    const int lm = lane & 15;  // m (A row) / n (B col) index
    const int lk = lane >> 4;  // k-group
    short8v bfrag[2][4];
#pragma unroll
    for (int ct = 0; ct < 2; ++ct) {
        int c = w * 32 + ct * 16 + lm;
#pragma unroll
        for (int q = 0; q < 4; ++q) {
            short8v f;
#pragma unroll
            for (int j = 0; j < 8; ++j) {
                int k = q * 32 + lk * 8 + j;
                f[j] = (short)f2bf(W[k * DIM + c]);
            }
            bfrag[ct][q] = f;
        }
    }
    const float asv0 = att_s[w * 32 + lm] * LOG2E;
    const float asv1 = att_s[w * 32 + 16 + lm] * LOG2E;
    const float adv0 = att_d[w * 32 + lm] * LOG2E;
    const float adv1 = att_d[w * 32 + 16 + lm] * LOG2E;

    const int nchunk = (n + 15) >> 4;
    for (int chunk = blockIdx.x; chunk < nchunk; chunk += gridDim.x) {
        const int r0 = chunk * 16;
        {   // stage 16 rows of x -> bf16 LDS (coalesced 32B/thread)
            int row = tid >> 4;
            int c8 = (tid & 15) * 8;
            int rg = min(r0 + row, n - 1);
            const float4* xp = (const float4*)(x + (size_t)rg * DIM + c8);
            float4 v0 = xp[0], v1 = xp[1];
            short8v t;
            t[0] = (short)f2bf(v0.x); t[1] = (short)f2bf(v0.y);
            t[2] = (short)f2bf(v0.z); t[3] = (short)f2bf(v0.w);
            t[4] = (short)f2bf(v1.x); t[5] = (short)f2bf(v1.y);
            t[6] = (short)f2bf(v1.z); t[7] = (short)f2bf(v1.w);
            *(short8v*)(&xs[row][c8]) = t;
        }
        __syncthreads();
        f32x4 acc0 = {0.f, 0.f, 0.f, 0.f}, acc1 = {0.f, 0.f, 0.f, 0.f};
#pragma unroll
        for (int q = 0; q < 4; ++q) {
            short8v a = *(const short8v*)(&xs[lm][q * 32 + lk * 8]);
            acc0 = __builtin_amdgcn_mfma_f32_16x16x32_bf16(a, bfrag[0][q], acc0, 0, 0, 0);
            acc1 = __builtin_amdgcn_mfma_f32_16x16x32_bf16(a, bfrag[1][q], acc1, 0, 0, 0);
        }
        __syncthreads();  // xs consumed; safe to restage next chunk
        float ps[4], qs[4];
#pragma unroll
        for (int j = 0; j < 4; ++j) {
            ps[j] = acc0[j] * asv0 + acc1[j] * asv1;
            qs[j] = acc0[j] * adv0 + acc1[j] * adv1;
        }
#pragma unroll
        for (int m = 1; m < 16; m <<= 1) {
#pragma unroll
            for (int j = 0; j < 4; ++j) {
                ps[j] += __shfl_xor(ps[j], m);
                qs[j] += __shfl_xor(qs[j], m);
            }
        }
#pragma unroll
        for (int j = 0; j < 4; ++j) {
            int r = r0 + 4 * lk + j;
            if (r < n) {
                hpk[(size_t)r * 64 + 16 * w + lm] =
                    (unsigned int)f2bf(acc0[j]) | ((unsigned int)f2bf(acc1[j]) << 16);
                if (lm == 0) {
                    asrc[r * 4 + w] = ps[j];
                    adst[r * 4 + w] = qs[j];
                }
            }
        }
    }
}

// ---------------- K2: init deg=1 (self loop) and zero BN stats ----------------
__global__ void k_init(int* __restrict__ deg, float* __restrict__ stats, int n) {
    int t = blockIdx.x * blockDim.x + threadIdx.x;
    if (t < n) deg[t] = 1;
    if (t < 256) stats[t] = 0.f;
}

// ---------------- K3: XCD-affine windowed histogram of dst (R13-verified ~-15us)
__global__ __launch_bounds__(256) void k_hist(const int* __restrict__ dst,
                                              int* __restrict__ deg, int E, int n) {
    const int g = blockIdx.x & 7;
    const int gb = blockIdx.x >> 3;
    const int nblk = gridDim.x >> 3;
    const int wsz = (n + 7) >> 3;
    const int lo = g * wsz;
    const int hi = min(lo + wsz, n);
    const int step = nblk * 256;
    for (int t = gb * 256 + threadIdx.x; t < E; t += step) {
        int d = dst[t];
        if (d >= lo && d < hi) atomicAdd(&deg[d], 1);
    }
}

// ---------------- K4abc: device-wide exclusive scan of deg (1024 elems/block) --
__global__ __launch_bounds__(256) void k_scan_part(const int* __restrict__ deg,
                                                   int* __restrict__ bsum, int n) {
    int idx = blockIdx.x * 1024 + threadIdx.x * 4;
    int4 v = {0, 0, 0, 0};
    if (idx + 3 < n) v = *(const int4*)(deg + idx);
    else {
        if (idx + 0 < n) v.x = deg[idx + 0];
        if (idx + 1 < n) v.y = deg[idx + 1];
        if (idx + 2 < n) v.z = deg[idx + 2];
    }
    int s = v.x + v.y + v.z + v.w;
#pragma unroll
    for (int m = 1; m < 64; m <<= 1) s += __shfl_xor(s, m);
    __shared__ int ws[4];
    if ((threadIdx.x & 63) == 0) ws[threadIdx.x >> 6] = s;
    __syncthreads();
    if (threadIdx.x == 0) bsum[blockIdx.x] = ws[0] + ws[1] + ws[2] + ws[3];
}

__global__ __launch_bounds__(256) void k_scan_tops(int* __restrict__ bsum, int B) {
    __shared__ int lds[256];
    int t = threadIdx.x;
    int v = (t < B) ? bsum[t] : 0;
    lds[t] = v;
    __syncthreads();
    int acc = v;
    for (int ofs = 1; ofs < 256; ofs <<= 1) {
        int u = (t >= ofs) ? lds[t - ofs] : 0;
        __syncthreads();
        acc += u;
        lds[t] = acc;
        __syncthreads();
    }
    if (t < B) bsum[t] = acc - v;  // exclusive block offsets (in place)
}

__global__ __launch_bounds__(256) void k_scan_add(const int* __restrict__ deg,
                                                  const int* __restrict__ bsum,
                                                  int* __restrict__ row_start,
                                                  int* __restrict__ cursor, int n, int total) {
    int t = threadIdx.x;
    int idx = blockIdx.x * 1024 + t * 4;
    int4 v = {0, 0, 0, 0};
    if (idx + 3 < n) v = *(const int4*)(deg + idx);
    else {
        if (idx + 0 < n) v.x = deg[idx + 0];
        if (idx + 1 < n) v.y = deg[idx + 1];
        if (idx + 2 < n) v.z = deg[idx + 2];
    }
    int s = v.x + v.y + v.z + v.w;
    __shared__ int lds[256];
    lds[t] = s;
    __syncthreads();
    int acc = s;
    for (int ofs = 1; ofs < 256; ofs <<= 1) {
        int u = (t >= ofs) ? lds[t - ofs] : 0;
        __syncthreads();
        acc += u;
        lds[t] = acc;
        __syncthreads();
    }
    int excl = bsum[blockIdx.x] + acc - s;
    int4 rs;
    rs.x = excl;
    rs.y = rs.x + v.x;
    rs.z = rs.y + v.y;
    rs.w = rs.z + v.z;
    if (idx + 3 < n) {
        *(int4*)(row_start + idx) = rs;
        *(int4*)(cursor + idx) = rs;
    } else {
        if (idx + 0 < n) { row_start[idx + 0] = rs.x; cursor[idx + 0] = rs.x; }
        if (idx + 1 < n) { row_start[idx + 1] = rs.y; cursor[idx + 1] = rs.y; }
        if (idx + 2 < n) { row_start[idx + 2] = rs.z; cursor[idx + 2] = rs.z; }
    }
    if (blockIdx.x == 0 && t == 0) row_start[n] = total;
}

// ---------------- K5: XCD-affine windowed scatter + softmax-weight precompute.
__global__ __launch_bounds__(256) void k_scatter(const int* __restrict__ src,
                                                 const int* __restrict__ dst,
                                                 const float4* __restrict__ asrc4,
                                                 const float4* __restrict__ adst4,
                                                 int* __restrict__ cursor,
                                                 int* __restrict__ csr,
                                                 uint2* __restrict__ pw,
                                                 int E, int n) {
    const int g = blockIdx.x & 7;
    const int gb = blockIdx.x >> 3;
    const int nblk = gridDim.x >> 3;
    const int wsz = (n + 7) >> 3;
    const int lo = g * wsz;
    const int hi = min(lo + wsz, n);
    const int total = E + n;
    const int step = nblk * 256;
    for (int t = gb * 256 + threadIdx.x; t < total; t += step) {
        int d = (t < E) ? dst[t] : (t - E);
        if (d >= lo && d < hi) {
            int sv = (t < E) ? src[t] : d;
            float4 a = asrc4[sv];   // 1.6MB, L2-resident
            float4 b = adst4[d];    // windowed -> L2-local
            float p0 = EXP2(leaky(a.x + b.x));
            float p1 = EXP2(leaky(a.y + b.y));
            float p2 = EXP2(leaky(a.z + b.z));
            float p3 = EXP2(leaky(a.w + b.w));
            int slot = atomicAdd(&cursor[d], 1);
            csr[slot] = sv;
            uint2 o;
            o.x = (unsigned int)f2bf(p0) | ((unsigned int)f2bf(p1) << 16);
            o.y = (unsigned int)f2bf(p2) | ((unsigned int)f2bf(p3) << 16);
            pw[slot] = o;
        }
    }
}

// ---------------- K6: per-dst-node aggregation, weights precomputed.
// R12/R14 inner body (empirical best: clamp-masked 16-edge batches) +
// XCD-affine node windows (streams/row_start/csr/pw/prev confined per-XCD;
// csr/pw likely still L2-resident from k_scatter's matching window) +
// PACKED: ypre stored as bf16x2 (halves write tier; stats stay exact f32).
template <bool PACKED>
__global__ __launch_bounds__(256) void k_agg(const unsigned int* __restrict__ hw,
                                             const unsigned short* __restrict__ pwh,
                                             const int* __restrict__ row_start,
                                             const int* __restrict__ csr,
                                             const float* __restrict__ prev,
                                             const float* __restrict__ bias,
                                             float* __restrict__ ypre,
                                             unsigned int* __restrict__ ypb,
                                             float* __restrict__ stats, int n) {
    const int lane = threadIdx.x & 63;
    const int hd = lane >> 4;                 // head
    const int ch = 32 * hd + (lane & 15);     // channel pair {ch, ch+16}
    const int g = blockIdx.x & 7;             // XCD window
    const int gb = blockIdx.x >> 3;
    const int nblk = gridDim.x >> 3;
    const int wsz = (n + 7) >> 3;
    const int lo = g * wsz;
    const int hi = min(lo + wsz, n);
    const int wig = gb * 4 + (threadIdx.x >> 6);  // wave in group
    const int nwg = nblk * 4;
    const float bb0 = bias[ch], bb1 = bias[ch + 16];
    float bsum0 = 0.f, bsq0 = 0.f, bsum1 = 0.f, bsq1 = 0.f;
    for (int i0 = lo + wig; i0 < hi; i0 += nwg) {
        int i = __builtin_amdgcn_readfirstlane(i0);
        int e0 = row_start[i], e1 = row_start[i + 1];
        float s = 0.f, acc0 = 0.f, acc1 = 0.f;
        for (int e = e0; e < e1; e += 16) {
            int j[16];
            float p[16];
            unsigned int hp[16];
#pragma unroll
            for (int r = 0; r < 16; ++r) {
                int ec = min(e + r, e1 - 1);
                j[r] = csr[ec];
                p[r] = bf2f(pwh[ec * 4 + hd]);
            }
#pragma unroll
            for (int r = 0; r < 16; ++r) hp[r] = hw[(size_t)j[r] * 64 + lane];
#pragma unroll
            for (int r = 0; r < 16; ++r) {
                float pp = (e + r < e1) ? p[r] : 0.f;
                s += pp;
                acc0 = fmaf(pp, __uint_as_float(hp[r] << 16), acc0);
                acc1 = fmaf(pp, __uint_as_float(hp[r] & 0xffff0000u), acc1);
            }
        }
        float rs = 1.0f / s;
        size_t base = (size_t)i * DIM;
        float o0 = fmaf(acc0, rs, bb0 + prev[base + ch]);
        float o1 = fmaf(acc1, rs, bb1 + prev[base + ch + 16]);
        if (PACKED) {
            ypb[(size_t)i * 64 + lane] =
                (unsigned int)f2bf(o0) | ((unsigned int)f2bf(o1) << 16);
        } else {
            ypre[base + ch] = o0;
            ypre[base + ch + 16] = o1;
        }
        bsum0 += o0; bsq0 = fmaf(o0, o0, bsq0);
        bsum1 += o1; bsq1 = fmaf(o1, o1, bsq1);
    }
    __shared__ float red[4][256];
    red[0][threadIdx.x] = bsum0;
    red[1][threadIdx.x] = bsq0;
    red[2][threadIdx.x] = bsum1;
    red[3][threadIdx.x] = bsq1;
    __syncthreads();
    if (threadIdx.x < 64) {
        int t = threadIdx.x;
        int c = 32 * (t >> 4) + (t & 15);
        float v0 = red[0][t] + red[0][t + 64] + red[0][t + 128] + red[0][t + 192];
        float v1 = red[1][t] + red[1][t + 64] + red[1][t + 128] + red[1][t + 192];
        float v2 = red[2][t] + red[2][t + 64] + red[2][t + 128] + red[2][t + 192];
        float v3 = red[3][t] + red[3][t + 64] + red[3][t + 128] + red[3][t + 192];
        atomicAdd(&stats[c], v0);             // sum, channel c
        atomicAdd(&stats[c + 16], v2);        // sum, channel c+16
        atomicAdd(&stats[128 + c], v1);       // sumsq, channel c
        atomicAdd(&stats[128 + c + 16], v3);  // sumsq, channel c+16
    }
}

// ---------------- K7: finalize BN scale/shift ----------------
__global__ void k_bnfin(const float* __restrict__ stats, const float* __restrict__ gamma,
                        const float* __restrict__ beta, float* __restrict__ AB, int n) {
    int c = threadIdx.x;  // 128 threads
    float fn = (float)n;
    float mean = stats[c] / fn;
    float var = stats[128 + c] / fn - mean * mean;
    float a = gamma[c] * rsqrtf(var + EPS);
    AB[c] = a;
    AB[128 + c] = beta[c] - mean * a;
}

// ---------------- K8a: packed path — read bf16x2 ypb, BN+relu, write f32 ----
__global__ __launch_bounds__(256) void k_final_pk(const unsigned int* __restrict__ ypb,
                                                  const float* __restrict__ AB,
                                                  float* __restrict__ yout, int totalw) {
    int t0 = blockIdx.x * blockDim.x + threadIdx.x;
    int stride = gridDim.x * blockDim.x;
    for (int t = t0; t < totalw; t += stride) {
        unsigned int wv = ypb[t];
        int u = t & 63;
        int row = t >> 6;
        int c = 32 * (u >> 4) + (u & 15);
        float o0 = bf2f((unsigned short)(wv & 0xffffu));
        float o1 = bf2f((unsigned short)(wv >> 16));
        float r0 = fmaf(o0, AB[c], AB[128 + c]);
        float r1 = fmaf(o1, AB[c + 16], AB[128 + c + 16]);
        yout[(size_t)row * DIM + c] = r0 > 0.f ? r0 : 0.f;
        yout[(size_t)row * DIM + c + 16] = r1 > 0.f ? r1 : 0.f;
    }
}

// ---------------- K8b: fallback — in-place f32 BN+relu ----------------
__global__ __launch_bounds__(256) void k_final(float* __restrict__ y,
                                               const float* __restrict__ AB, int total4) {
    int t0 = blockIdx.x * blockDim.x + threadIdx.x;
    int stride = gridDim.x * blockDim.x;
    for (int t = t0; t < total4; t += stride) {
        float4 v = ((float4*)y)[t];
        int c0 = (t * 4) & 127;
        v.x = fmaf(v.x, AB[c0 + 0], AB[128 + c0 + 0]);
        v.y = fmaf(v.y, AB[c0 + 1], AB[128 + c0 + 1]);
        v.z = fmaf(v.z, AB[c0 + 2], AB[128 + c0 + 2]);
        v.w = fmaf(v.w, AB[c0 + 3], AB[128 + c0 + 3]);
        v.x = v.x > 0.f ? v.x : 0.f;
        v.y = v.y > 0.f ? v.y : 0.f;
        v.z = v.z > 0.f ? v.z : 0.f;
        v.w = v.w > 0.f ? v.w : 0.f;
        ((float4*)y)[t] = v;
    }
}

extern "C" void kernel_launch(void* const* d_in, const int* in_sizes, int n_in,
                              void* d_out, int out_size, void* d_ws, size_t ws_size,
                              hipStream_t stream) {
    const float* prev  = (const float*)d_in[0];
    const float* x     = (const float*)d_in[1];
    const int*   ei    = (const int*)d_in[2];
    const float* W     = (const float*)d_in[3];
    const float* att_s = (const float*)d_in[4];
    const float* att_d = (const float*)d_in[5];
    const float* bias  = (const float*)d_in[6];
    const float* gamma = (const float*)d_in[7];
    const float* beta  = (const float*)d_in[8];
    const int n = in_sizes[0] / DIM;
    const int E = in_sizes[2] / 2;
    const int* src = ei;
    const int* dst = ei + E;

    char* p = (char*)d_ws;
    auto alloc = [&](size_t bytes) {
        void* q = (void*)p;
        p += (bytes + 255) & ~(size_t)255;
        return q;
    };
    unsigned int* hpk = (unsigned int*)alloc((size_t)n * 64 * 4);
    float* asrc      = (float*)alloc((size_t)n * 4 * 4);
    float* adst      = (float*)alloc((size_t)n * 4 * 4);
    int*   deg       = (int*)alloc((size_t)(n + 1) * 4);
    int*   row_start = (int*)alloc((size_t)(n + 1) * 4);
    int*   cursor    = (int*)alloc((size_t)(n + 1) * 4);
    int*   csr       = (int*)alloc((size_t)(E + n + 16) * 4);
    uint2* pw        = (uint2*)alloc((size_t)(E + n + 16) * 8);  // bf16x4 / edge
    int*   bsum      = (int*)alloc(1024 * 4);
    float* stats     = (float*)alloc(256 * 4);
    float* AB        = (float*)alloc(256 * 4);
    unsigned int* ypb = (unsigned int*)alloc((size_t)n * 64 * 4);  // bf16x2 ypre
    const bool packed = ((size_t)(p - (char*)d_ws) <= ws_size);
    float* yout      = (float*)d_out;

    int B = (n + 1023) / 1024;  // scan blocks (<=256 for n<=262144)
    k_init<<<dim3((n + 255) / 256), dim3(256), 0, stream>>>(deg, stats, n);
    k_gemm<<<dim3(1024), dim3(256), 0, stream>>>(x, W, att_s, att_d, hpk, asrc, adst, n);
    k_hist<<<dim3(2048), dim3(256), 0, stream>>>(dst, deg, E, n);
    k_scan_part<<<dim3(B), dim3(256), 0, stream>>>(deg, bsum, n);
    k_scan_tops<<<dim3(1), dim3(256), 0, stream>>>(bsum, B);
    k_scan_add<<<dim3(B), dim3(256), 0, stream>>>(deg, bsum, row_start, cursor, n, E + n);
    k_scatter<<<dim3(2048), dim3(256), 0, stream>>>(src, dst, (const float4*)asrc,
                                                    (const float4*)adst, cursor, csr, pw, E, n);
    if (packed) {
        k_agg<true><<<dim3(2048), dim3(256), 0, stream>>>(
            hpk, (const unsigned short*)pw, row_start, csr, prev, bias, yout, ypb, stats, n);
        k_bnfin<<<dim3(1), dim3(128), 0, stream>>>(stats, gamma, beta, AB, n);
        k_final_pk<<<dim3(2048), dim3(256), 0, stream>>>(ypb, AB, yout, n * 64);
    } else {
        k_agg<false><<<dim3(2048), dim3(256), 0, stream>>>(
            hpk, (const unsigned short*)pw, row_start, csr, prev, bias, yout, ypb, stats, n);
        k_bnfin<<<dim3(1), dim3(128), 0, stream>>>(stats, gamma, beta, AB, n);
        k_final<<<dim3(2048), dim3(256), 0, stream>>>(yout, AB, n * DIM / 4);
    }
}

// Round 18
// 297.333 us; speedup vs baseline: 1.0917x; 1.0028x over previous
//
#include <hip/hip_runtime.h>
#include <math.h>

#define DIM 128
#define NEG 0.2f
#define EPS 1e-5f
#define LOG2E 1.4426950408889634f

#if __has_builtin(__builtin_amdgcn_exp2f)
#define EXP2(x) __builtin_amdgcn_exp2f(x)
#else
#define EXP2(x) exp2f(x)
#endif

typedef __attribute__((ext_vector_type(8))) short short8v;  // bf16x8 MFMA frag
typedef __attribute__((ext_vector_type(4))) float f32x4;

static __device__ __forceinline__ float leaky(float a) { return a > 0.f ? a : NEG * a; }
static __device__ __forceinline__ float bf2f(unsigned short u) {
    return __uint_as_float(((unsigned int)u) << 16);
}
static __device__ __forceinline__ unsigned short f2bf(float f) {
    unsigned int u = __float_as_uint(f);
    unsigned int r = (u + 0x7fffu + ((u >> 16) & 1u)) >> 16;  // RNE
    return (unsigned short)r;
}

// ---------------- K1: h = x@W via MFMA bf16. Block=256 (4 waves).
// Wave w owns head w = cols [32w, 32w+32). B-frags (W) live in registers;
// grid=1024 amortizes the 64KB W prologue over ~6 chunks.
// hpk word u of row r = channels {c, c+16}, c = 32*(u>>4) + (u&15).
__global__ __launch_bounds__(256) void k_gemm(const float* __restrict__ x,
                                              const float* __restrict__ W,
                                              const float* __restrict__ att_s,
                                              const float* __restrict__ att_d,
                                              unsigned int* __restrict__ hpk,
                                              float* __restrict__ asrc,
                                              float* __restrict__ adst, int n) {
    __shared__ __align__(16) unsigned short xs[16][136];  // 16 rows bf16, padded
    const int tid = threadIdx.x;
    const int w = tid >> 6;    // wave = head
    const int lane = tid & 63;
    const int lm = lane & 15;  // m (A row) / n (B col) index
    const int lk = lane >> 4;  // k-group
    short8v bfrag[2][4];
#pragma unroll
    for (int ct = 0; ct < 2; ++ct) {
        int c = w * 32 + ct * 16 + lm;
#pragma unroll
        for (int q = 0; q < 4; ++q) {
            short8v f;
#pragma unroll
            for (int j = 0; j < 8; ++j) {
                int k = q * 32 + lk * 8 + j;
                f[j] = (short)f2bf(W[k * DIM + c]);
            }
            bfrag[ct][q] = f;
        }
    }
    const float asv0 = att_s[w * 32 + lm] * LOG2E;
    const float asv1 = att_s[w * 32 + 16 + lm] * LOG2E;
    const float adv0 = att_d[w * 32 + lm] * LOG2E;
    const float adv1 = att_d[w * 32 + 16 + lm] * LOG2E;

    const int nchunk = (n + 15) >> 4;
    for (int chunk = blockIdx.x; chunk < nchunk; chunk += gridDim.x) {
        const int r0 = chunk * 16;
        {   // stage 16 rows of x -> bf16 LDS (coalesced 32B/thread)
            int row = tid >> 4;
            int c8 = (tid & 15) * 8;
            int rg = min(r0 + row, n - 1);
            const float4* xp = (const float4*)(x + (size_t)rg * DIM + c8);
            float4 v0 = xp[0], v1 = xp[1];
            short8v t;
            t[0] = (short)f2bf(v0.x); t[1] = (short)f2bf(v0.y);
            t[2] = (short)f2bf(v0.z); t[3] = (short)f2bf(v0.w);
            t[4] = (short)f2bf(v1.x); t[5] = (short)f2bf(v1.y);
            t[6] = (short)f2bf(v1.z); t[7] = (short)f2bf(v1.w);
            *(short8v*)(&xs[row][c8]) = t;
        }
        __syncthreads();
        f32x4 acc0 = {0.f, 0.f, 0.f, 0.f}, acc1 = {0.f, 0.f, 0.f, 0.f};
#pragma unroll
        for (int q = 0; q < 4; ++q) {
            short8v a = *(const short8v*)(&xs[lm][q * 32 + lk * 8]);
            acc0 = __builtin_amdgcn_mfma_f32_16x16x32_bf16(a, bfrag[0][q], acc0, 0, 0, 0);
            acc1 = __builtin_amdgcn_mfma_f32_16x16x32_bf16(a, bfrag[1][q], acc1, 0, 0, 0);
        }
        __syncthreads();  // xs consumed; safe to restage next chunk
        float ps[4], qs[4];
#pragma unroll
        for (int j = 0; j < 4; ++j) {
            ps[j] = acc0[j] * asv0 + acc1[j] * asv1;
            qs[j] = acc0[j] * adv0 + acc1[j] * adv1;
        }
#pragma unroll
        for (int m = 1; m < 16; m <<= 1) {
#pragma unroll
            for (int j = 0; j < 4; ++j) {
                ps[j] += __shfl_xor(ps[j], m);
                qs[j] += __shfl_xor(qs[j], m);
            }
        }
#pragma unroll
        for (int j = 0; j < 4; ++j) {
            int r = r0 + 4 * lk + j;
            if (r < n) {
                hpk[(size_t)r * 64 + 16 * w + lm] =
                    (unsigned int)f2bf(acc0[j]) | ((unsigned int)f2bf(acc1[j]) << 16);
                if (lm == 0) {
                    asrc[r * 4 + w] = ps[j];
                    adst[r * 4 + w] = qs[j];
                }
            }
        }
    }
}

// ---------------- K2: init deg=1 (self loop) and zero BN stats ----------------
__global__ void k_init(int* __restrict__ deg, float* __restrict__ stats, int n) {
    int t = blockIdx.x * blockDim.x + threadIdx.x;
    if (t < n) deg[t] = 1;
    if (t < 256) stats[t] = 0.f;
}

// ---------------- K3: XCD-affine windowed histogram of dst (R13-verified ~-15us)
__global__ __launch_bounds__(256) void k_hist(const int* __restrict__ dst,
                                              int* __restrict__ deg, int E, int n) {
    const int g = blockIdx.x & 7;
    const int gb = blockIdx.x >> 3;
    const int nblk = gridDim.x >> 3;
    const int wsz = (n + 7) >> 3;
    const int lo = g * wsz;
    const int hi = min(lo + wsz, n);
    const int step = nblk * 256;
    for (int t = gb * 256 + threadIdx.x; t < E; t += step) {
        int d = dst[t];
        if (d >= lo && d < hi) atomicAdd(&deg[d], 1);
    }
}

// ---------------- K4abc: device-wide exclusive scan of deg (1024 elems/block) --
__global__ __launch_bounds__(256) void k_scan_part(const int* __restrict__ deg,
                                                   int* __restrict__ bsum, int n) {
    int idx = blockIdx.x * 1024 + threadIdx.x * 4;
    int4 v = {0, 0, 0, 0};
    if (idx + 3 < n) v = *(const int4*)(deg + idx);
    else {
        if (idx + 0 < n) v.x = deg[idx + 0];
        if (idx + 1 < n) v.y = deg[idx + 1];
        if (idx + 2 < n) v.z = deg[idx + 2];
    }
    int s = v.x + v.y + v.z + v.w;
#pragma unroll
    for (int m = 1; m < 64; m <<= 1) s += __shfl_xor(s, m);
    __shared__ int ws[4];
    if ((threadIdx.x & 63) == 0) ws[threadIdx.x >> 6] = s;
    __syncthreads();
    if (threadIdx.x == 0) bsum[blockIdx.x] = ws[0] + ws[1] + ws[2] + ws[3];
}

__global__ __launch_bounds__(256) void k_scan_tops(int* __restrict__ bsum, int B) {
    __shared__ int lds[256];
    int t = threadIdx.x;
    int v = (t < B) ? bsum[t] : 0;
    lds[t] = v;
    __syncthreads();
    int acc = v;
    for (int ofs = 1; ofs < 256; ofs <<= 1) {
        int u = (t >= ofs) ? lds[t - ofs] : 0;
        __syncthreads();
        acc += u;
        lds[t] = acc;
        __syncthreads();
    }
    if (t < B) bsum[t] = acc - v;  // exclusive block offsets (in place)
}

__global__ __launch_bounds__(256) void k_scan_add(const int* __restrict__ deg,
                                                  const int* __restrict__ bsum,
                                                  int* __restrict__ row_start,
                                                  int* __restrict__ cursor, int n, int total) {
    int t = threadIdx.x;
    int idx = blockIdx.x * 1024 + t * 4;
    int4 v = {0, 0, 0, 0};
    if (idx + 3 < n) v = *(const int4*)(deg + idx);
    else {
        if (idx + 0 < n) v.x = deg[idx + 0];
        if (idx + 1 < n) v.y = deg[idx + 1];
        if (idx + 2 < n) v.z = deg[idx + 2];
    }
    int s = v.x + v.y + v.z + v.w;
    __shared__ int lds[256];
    lds[t] = s;
    __syncthreads();
    int acc = s;
    for (int ofs = 1; ofs < 256; ofs <<= 1) {
        int u = (t >= ofs) ? lds[t - ofs] : 0;
        __syncthreads();
        acc += u;
        lds[t] = acc;
        __syncthreads();
    }
    int excl = bsum[blockIdx.x] + acc - s;
    int4 rs;
    rs.x = excl;
    rs.y = rs.x + v.x;
    rs.z = rs.y + v.y;
    rs.w = rs.z + v.z;
    if (idx + 3 < n) {
        *(int4*)(row_start + idx) = rs;
        *(int4*)(cursor + idx) = rs;
    } else {
        if (idx + 0 < n) { row_start[idx + 0] = rs.x; cursor[idx + 0] = rs.x; }
        if (idx + 1 < n) { row_start[idx + 1] = rs.y; cursor[idx + 1] = rs.y; }
        if (idx + 2 < n) { row_start[idx + 2] = rs.z; cursor[idx + 2] = rs.z; }
    }
    if (blockIdx.x == 0 && t == 0) row_start[n] = total;
}

// ---------------- K5: XCD-affine windowed scatter + softmax-weight precompute.
// FUSED 12B record per slot: {src, p01, p23} stored contiguously -> ONE
// random line-touch per edge (was two: csr 4B + pw 8B on separate lines,
// WRITE_SIZE 159MB @ R17). Window: group g=blockIdx&7 owns [g*wsz,(g+1)*wsz).
__global__ __launch_bounds__(256) void k_scatter(const int* __restrict__ src,
                                                 const int* __restrict__ dst,
                                                 const float4* __restrict__ asrc4,
                                                 const float4* __restrict__ adst4,
                                                 int* __restrict__ cursor,
                                                 int* __restrict__ rec,
                                                 int E, int n) {
    const int g = blockIdx.x & 7;
    const int gb = blockIdx.x >> 3;
    const int nblk = gridDim.x >> 3;
    const int wsz = (n + 7) >> 3;
    const int lo = g * wsz;
    const int hi = min(lo + wsz, n);
    const int total = E + n;
    const int step = nblk * 256;
    for (int t = gb * 256 + threadIdx.x; t < total; t += step) {
        int d = (t < E) ? dst[t] : (t - E);
        if (d >= lo && d < hi) {
            int sv = (t < E) ? src[t] : d;
            float4 a = asrc4[sv];   // 1.6MB, L2-resident
            float4 b = adst4[d];    // windowed -> L2-local
            float p0 = EXP2(leaky(a.x + b.x));
            float p1 = EXP2(leaky(a.y + b.y));
            float p2 = EXP2(leaky(a.z + b.z));
            float p3 = EXP2(leaky(a.w + b.w));
            int slot = atomicAdd(&cursor[d], 1);
            int b3 = slot * 3;
            rec[b3 + 0] = sv;
            rec[b3 + 1] = (int)((unsigned int)f2bf(p0) | ((unsigned int)f2bf(p1) << 16));
            rec[b3 + 2] = (int)((unsigned int)f2bf(p2) | ((unsigned int)f2bf(p3) << 16));
        }
    }
}

// ---------------- K6: per-dst-node aggregation, weights precomputed.
// R12/R14 inner body (empirical best; 40 VGPR — do not restructure) reading
// the fused 12B record stream (j + head's bf16 p from the same 64B line).
// XCD-affine node windows; PACKED: ypre stored bf16x2 (stats stay exact f32).
template <bool PACKED>
__global__ __launch_bounds__(256) void k_agg(const unsigned int* __restrict__ hw,
                                             const int* __restrict__ rec,
                                             const int* __restrict__ row_start,
                                             const float* __restrict__ prev,
                                             const float* __restrict__ bias,
                                             float* __restrict__ ypre,
                                             unsigned int* __restrict__ ypb,
                                             float* __restrict__ stats, int n) {
    const int lane = threadIdx.x & 63;
    const int hd = lane >> 4;                 // head
    const int ch = 32 * hd + (lane & 15);     // channel pair {ch, ch+16}
    const int g = blockIdx.x & 7;             // XCD window
    const int gb = blockIdx.x >> 3;
    const int nblk = gridDim.x >> 3;
    const int wsz = (n + 7) >> 3;
    const int lo = g * wsz;
    const int hi = min(lo + wsz, n);
    const int wig = gb * 4 + (threadIdx.x >> 6);  // wave in group
    const int nwg = nblk * 4;
    const unsigned short* __restrict__ rech = (const unsigned short*)rec;
    const float bb0 = bias[ch], bb1 = bias[ch + 16];
    float bsum0 = 0.f, bsq0 = 0.f, bsum1 = 0.f, bsq1 = 0.f;
    for (int i0 = lo + wig; i0 < hi; i0 += nwg) {
        int i = __builtin_amdgcn_readfirstlane(i0);
        int e0 = row_start[i], e1 = row_start[i + 1];
        float s = 0.f, acc0 = 0.f, acc1 = 0.f;
        for (int e = e0; e < e1; e += 16) {
            int j[16];
            float p[16];
            unsigned int hp[16];
#pragma unroll
            for (int r = 0; r < 16; ++r) {
                int ec = min(e + r, e1 - 1);
                j[r] = rec[ec * 3];
                p[r] = bf2f(rech[ec * 6 + 2 + hd]);
            }
#pragma unroll
            for (int r = 0; r < 16; ++r) hp[r] = hw[(size_t)j[r] * 64 + lane];
#pragma unroll
            for (int r = 0; r < 16; ++r) {
                float pp = (e + r < e1) ? p[r] : 0.f;
                s += pp;
                acc0 = fmaf(pp, __uint_as_float(hp[r] << 16), acc0);
                acc1 = fmaf(pp, __uint_as_float(hp[r] & 0xffff0000u), acc1);
            }
        }
        float rs = 1.0f / s;
        size_t base = (size_t)i * DIM;
        float o0 = fmaf(acc0, rs, bb0 + prev[base + ch]);
        float o1 = fmaf(acc1, rs, bb1 + prev[base + ch + 16]);
        if (PACKED) {
            ypb[(size_t)i * 64 + lane] =
                (unsigned int)f2bf(o0) | ((unsigned int)f2bf(o1) << 16);
        } else {
            ypre[base + ch] = o0;
            ypre[base + ch + 16] = o1;
        }
        bsum0 += o0; bsq0 = fmaf(o0, o0, bsq0);
        bsum1 += o1; bsq1 = fmaf(o1, o1, bsq1);
    }
    __shared__ float red[4][256];
    red[0][threadIdx.x] = bsum0;
    red[1][threadIdx.x] = bsq0;
    red[2][threadIdx.x] = bsum1;
    red[3][threadIdx.x] = bsq1;
    __syncthreads();
    if (threadIdx.x < 64) {
        int t = threadIdx.x;
        int c = 32 * (t >> 4) + (t & 15);
        float v0 = red[0][t] + red[0][t + 64] + red[0][t + 128] + red[0][t + 192];
        float v1 = red[1][t] + red[1][t + 64] + red[1][t + 128] + red[1][t + 192];
        float v2 = red[2][t] + red[2][t + 64] + red[2][t + 128] + red[2][t + 192];
        float v3 = red[3][t] + red[3][t + 64] + red[3][t + 128] + red[3][t + 192];
        atomicAdd(&stats[c], v0);             // sum, channel c
        atomicAdd(&stats[c + 16], v2);        // sum, channel c+16
        atomicAdd(&stats[128 + c], v1);       // sumsq, channel c
        atomicAdd(&stats[128 + c + 16], v3);  // sumsq, channel c+16
    }
}

// ---------------- K7: finalize BN scale/shift ----------------
__global__ void k_bnfin(const float* __restrict__ stats, const float* __restrict__ gamma,
                        const float* __restrict__ beta, float* __restrict__ AB, int n) {
    int c = threadIdx.x;  // 128 threads
    float fn = (float)n;
    float mean = stats[c] / fn;
    float var = stats[128 + c] / fn - mean * mean;
    float a = gamma[c] * rsqrtf(var + EPS);
    AB[c] = a;
    AB[128 + c] = beta[c] - mean * a;
}

// ---------------- K8a: packed path — read bf16x2 ypb, BN+relu, write f32 ----
__global__ __launch_bounds__(256) void k_final_pk(const unsigned int* __restrict__ ypb,
                                                  const float* __restrict__ AB,
                                                  float* __restrict__ yout, int totalw) {
    int t0 = blockIdx.x * blockDim.x + threadIdx.x;
    int stride = gridDim.x * blockDim.x;
    for (int t = t0; t < totalw; t += stride) {
        unsigned int wv = ypb[t];
        int u = t & 63;
        int row = t >> 6;
        int c = 32 * (u >> 4) + (u & 15);
        float o0 = bf2f((unsigned short)(wv & 0xffffu));
        float o1 = bf2f((unsigned short)(wv >> 16));
        float r0 = fmaf(o0, AB[c], AB[128 + c]);
        float r1 = fmaf(o1, AB[c + 16], AB[128 + c + 16]);
        yout[(size_t)row * DIM + c] = r0 > 0.f ? r0 : 0.f;
        yout[(size_t)row * DIM + c + 16] = r1 > 0.f ? r1 : 0.f;
    }
}

// ---------------- K8b: fallback — in-place f32 BN+relu ----------------
__global__ __launch_bounds__(256) void k_final(float* __restrict__ y,
                                               const float* __restrict__ AB, int total4) {
    int t0 = blockIdx.x * blockDim.x + threadIdx.x;
    int stride = gridDim.x * blockDim.x;
    for (int t = t0; t < total4; t += stride) {
        float4 v = ((float4*)y)[t];
        int c0 = (t * 4) & 127;
        v.x = fmaf(v.x, AB[c0 + 0], AB[128 + c0 + 0]);
        v.y = fmaf(v.y, AB[c0 + 1], AB[128 + c0 + 1]);
        v.z = fmaf(v.z, AB[c0 + 2], AB[128 + c0 + 2]);
        v.w = fmaf(v.w, AB[c0 + 3], AB[128 + c0 + 3]);
        v.x = v.x > 0.f ? v.x : 0.f;
        v.y = v.y > 0.f ? v.y : 0.f;
        v.z = v.z > 0.f ? v.z : 0.f;
        v.w = v.w > 0.f ? v.w : 0.f;
        ((float4*)y)[t] = v;
    }
}

extern "C" void kernel_launch(void* const* d_in, const int* in_sizes, int n_in,
                              void* d_out, int out_size, void* d_ws, size_t ws_size,
                              hipStream_t stream) {
    const float* prev  = (const float*)d_in[0];
    const float* x     = (const float*)d_in[1];
    const int*   ei    = (const int*)d_in[2];
    const float* W     = (const float*)d_in[3];
    const float* att_s = (const float*)d_in[4];
    const float* att_d = (const float*)d_in[5];
    const float* bias  = (const float*)d_in[6];
    const float* gamma = (const float*)d_in[7];
    const float* beta  = (const float*)d_in[8];
    const int n = in_sizes[0] / DIM;
    const int E = in_sizes[2] / 2;
    const int* src = ei;
    const int* dst = ei + E;

    char* p = (char*)d_ws;
    auto alloc = [&](size_t bytes) {
        void* q = (void*)p;
        p += (bytes + 255) & ~(size_t)255;
        return q;
    };
    unsigned int* hpk = (unsigned int*)alloc((size_t)n * 64 * 4);
    float* asrc      = (float*)alloc((size_t)n * 4 * 4);
    float* adst      = (float*)alloc((size_t)n * 4 * 4);
    int*   deg       = (int*)alloc((size_t)(n + 1) * 4);
    int*   row_start = (int*)alloc((size_t)(n + 1) * 4);
    int*   cursor    = (int*)alloc((size_t)(n + 1) * 4);
    int*   rec       = (int*)alloc((size_t)(E + n + 16) * 12);  // {src,p01,p23}/edge
    int*   bsum      = (int*)alloc(1024 * 4);
    float* stats     = (float*)alloc(256 * 4);
    float* AB        = (float*)alloc(256 * 4);
    unsigned int* ypb = (unsigned int*)alloc((size_t)n * 64 * 4);  // bf16x2 ypre
    const bool packed = ((size_t)(p - (char*)d_ws) <= ws_size);
    float* yout      = (float*)d_out;

    int B = (n + 1023) / 1024;  // scan blocks (<=256 for n<=262144)
    k_init<<<dim3((n + 255) / 256), dim3(256), 0, stream>>>(deg, stats, n);
    k_gemm<<<dim3(1024), dim3(256), 0, stream>>>(x, W, att_s, att_d, hpk, asrc, adst, n);
    k_hist<<<dim3(2048), dim3(256), 0, stream>>>(dst, deg, E, n);
    k_scan_part<<<dim3(B), dim3(256), 0, stream>>>(deg, bsum, n);
    k_scan_tops<<<dim3(1), dim3(256), 0, stream>>>(bsum, B);
    k_scan_add<<<dim3(B), dim3(256), 0, stream>>>(deg, bsum, row_start, cursor, n, E + n);
    k_scatter<<<dim3(2048), dim3(256), 0, stream>>>(src, dst, (const float4*)asrc,
                                                    (const float4*)adst, cursor, rec, E, n);
    if (packed) {
        k_agg<true><<<dim3(2048), dim3(256), 0, stream>>>(
            hpk, rec, row_start, prev, bias, yout, ypb, stats, n);
        k_bnfin<<<dim3(1), dim3(128), 0, stream>>>(stats, gamma, beta, AB, n);
        k_final_pk<<<dim3(2048), dim3(256), 0, stream>>>(ypb, AB, yout, n * 64);
    } else {
        k_agg<false><<<dim3(2048), dim3(256), 0, stream>>>(
            hpk, rec, row_start, prev, bias, yout, ypb, stats, n);
        k_bnfin<<<dim3(1), dim3(128), 0, stream>>>(stats, gamma, beta, AB, n);
        k_final<<<dim3(2048), dim3(256), 0, stream>>>(yout, AB, n * DIM / 4);
    }
}